// Round 1
// baseline (400.947 us; speedup 1.0000x reference)
//
#include <hip/hip_runtime.h>
#include <hip/hip_bf16.h>
#include <cstdint>

// SelfAttention fused pipeline, MI355X gfx950.
// B=4, S=2048, D=1024. fp32 in/out; internal split-bf16 MFMA for precision-
// critical GEMMs (Q/K proj, QK^T), plain bf16 MFMA for V proj and PV.
//
// ws layout (bytes, MB-aligned):
//   [0,16)    q_hi   [16,32) q_lo   [32,48) k_hi   [48,64) k_lo   (bf16 [8192][1024])
//   [64,80)   vT bf16 [1024][8192]  (v transposed, per-batch stride 2048 cols)
//   [80,92)   Wt splits: wt_qh,wt_ql,wt_kh,wt_kl,wt_vh,wt_vl (2MB each, [f][d])
//   [92,124)  O fp32 [8192][1024]   (attention output, pre-LN)
//   [124,220) BIG region:
//       phase 1: qx_hi/lo, kx_hi/lo, vx_hi/lo (input splits, 16MB each)
//       phase 2: S fp32 [4][2048][2048] @124 (aliases qx/kx splits - done)
//                P bf16 [4][2048][2048] @188 (aliases vx splits - done)

typedef unsigned short u16;
typedef unsigned int   u32;
typedef __bf16 bf16x8 __attribute__((ext_vector_type(8)));
typedef float  f32x4  __attribute__((ext_vector_type(4)));
typedef u16    u16x4v __attribute__((ext_vector_type(4)));
typedef u16    u16x8v __attribute__((ext_vector_type(8)));

#define DEV __device__ __forceinline__

DEV u16 f2bf(float f){ u32 u = __builtin_bit_cast(u32, f); u += 0x7fffu + ((u >> 16) & 1u); return (u16)(u >> 16); }
DEV float bf2f(u16 h){ u32 u = ((u32)h) << 16; return __builtin_bit_cast(float, u); }

// async global->LDS, 16B per lane. LDS dest must be linear (uniform base + lane*16).
DEV void gld_lds16(const void* g, void* l){
  __builtin_amdgcn_global_load_lds(
      (const __attribute__((address_space(1))) u32*)(uintptr_t)g,
      (__attribute__((address_space(3))) u32*)(u32)(uintptr_t)l, 16, 0, 0);
}

// ---------------- elementwise split fp32 -> bf16 hi/lo ----------------
__global__ __launch_bounds__(256) void split_f32(const float* __restrict__ x,
                                                 u16* __restrict__ hi, u16* __restrict__ lo, int n){
  int i = (blockIdx.x * 256 + threadIdx.x) * 4;
  if (i >= n) return;
  float4 v = *(const float4*)(x + i);
  float a[4] = {v.x, v.y, v.z, v.w};
  u16x4v h, l;
#pragma unroll
  for (int j = 0; j < 4; j++){ u16 hh = f2bf(a[j]); h[j] = hh; l[j] = f2bf(a[j] - bf2f(hh)); }
  *(u16x4v*)(hi + i) = h;
  *(u16x4v*)(lo + i) = l;
}

// ------------- W [d][f] fp32 -> Wt_hi/lo [f][d] bf16 (transpose+split) -------------
__global__ __launch_bounds__(256) void transpose_split_w(const float* __restrict__ W,
                                                         u16* __restrict__ Th, u16* __restrict__ Tl, int D){
  __shared__ float t[32][33];
  int tx = threadIdx.x & 31, ty = threadIdx.x >> 5; // 32 x 8
  int bx = blockIdx.x * 32, by = blockIdx.y * 32;
#pragma unroll
  for (int j = 0; j < 4; j++) t[ty + j*8][tx] = W[(size_t)(by + ty + j*8) * D + bx + tx];
  __syncthreads();
#pragma unroll
  for (int j = 0; j < 4; j++){
    float v = t[tx][ty + j*8];                  // = W[by+tx][bx+ty+j*8]
    size_t idx = (size_t)(bx + ty + j*8) * D + by + tx;  // T[f][d]
    u16 h = f2bf(v);
    Th[idx] = h; Tl[idx] = f2bf(v - bf2f(h));
  }
}

// ---------------- MFMA GEMM: C[M][N] = A[M][K] * Bt[N][K]^T (+bias) ----------------
// SPLIT: A,B given as hi/lo bf16 pairs; 3-MFMA (hh + hl + lh) per step => ~fp32 product precision.
// OUTMODE: 0 = fp32 C[row*ldo+col]; 1 = split bf16 hi/lo; 2 = transposed bf16 C[col*ldo+row].
template<bool SPLIT, int OUTMODE, bool BIAS>
__global__ __launch_bounds__(256)
void gemm_bt(const u16* __restrict__ Ahi, const u16* __restrict__ Alo, int lda, long long sAz,
             const u16* __restrict__ Bhi, const u16* __restrict__ Blo, int ldb, long long sBz,
             const float* __restrict__ bias,
             void* __restrict__ out0, void* __restrict__ out1, int ldo, long long sOz,
             int M, int N, int K)
{
  constexpr int BM = 128, BN = 128, BK = 32;
  __shared__ u16 smem[(SPLIT ? 4 : 2) * BM * BK];
  u16* sA  = smem;
  u16* sB  = smem + BM * BK;
  u16* sA2 = SPLIT ? smem + 2 * BM * BK : nullptr;
  u16* sB2 = SPLIT ? smem + 3 * BM * BK : nullptr;

  const int tid  = threadIdx.x;
  const int lane = tid & 63;
  const int w    = tid >> 6;          // 4 waves, 2x2
  const int wm   = w >> 1, wn = w & 1;
  const int z    = blockIdx.z;
  const int m0   = blockIdx.y * BM;
  const int n0   = blockIdx.x * BN;

  const u16* Ah = Ahi + (long long)z * sAz + (size_t)m0 * lda;
  const u16* Bh = Bhi + (long long)z * sBz + (size_t)n0 * ldb;
  const u16* Al = SPLIT ? (Alo + (long long)z * sAz + (size_t)m0 * lda) : nullptr;
  const u16* Bl = SPLIT ? (Blo + (long long)z * sBz + (size_t)n0 * ldb) : nullptr;

  auto stage = [&](const u16* g, int ld, u16* s){
#pragma unroll
    for (int i = 0; i < 2; i++){
      int o = (tid + i * 256) * 16;        // byte offset within 8KB tile
      int r = o >> 6;                      // row (64B = 32 bf16 per row)
      int cb = o & 63;                     // byte col
      gld_lds16((const char*)g + (size_t)r * ld * 2 + cb, (char*)s + o);
    }
  };

  f32x4 acc[4][4] = {};

  for (int k0 = 0; k0 < K; k0 += BK){
    __syncthreads();   // prev iter's LDS reads done before overwrite
    stage(Ah + k0, lda, sA);
    stage(Bh + k0, ldb, sB);
    if (SPLIT){ stage(Al + k0, lda, sA2); stage(Bl + k0, ldb, sB2); }
    __syncthreads();   // drains vmcnt(0): LDS tiles ready

    const int lr  = lane & 15;
    const int lkb = (lane >> 4) * 16;      // byte offset of this lane's k-chunk (8 bf16)
    bf16x8 ah[4], bh[4], al[4], bl[4];
#pragma unroll
    for (int i = 0; i < 4; i++){
      ah[i] = *(const bf16x8*)((const char*)sA + ((wm * 64 + i * 16 + lr) * 64 + lkb));
      bh[i] = *(const bf16x8*)((const char*)sB + ((wn * 64 + i * 16 + lr) * 64 + lkb));
      if (SPLIT){
        al[i] = *(const bf16x8*)((const char*)sA2 + ((wm * 64 + i * 16 + lr) * 64 + lkb));
        bl[i] = *(const bf16x8*)((const char*)sB2 + ((wn * 64 + i * 16 + lr) * 64 + lkb));
      }
    }
#pragma unroll
    for (int i = 0; i < 4; i++)
#pragma unroll
      for (int j = 0; j < 4; j++){
        acc[i][j] = __builtin_amdgcn_mfma_f32_16x16x32_bf16(ah[i], bh[j], acc[i][j], 0, 0, 0);
        if (SPLIT){
          acc[i][j] = __builtin_amdgcn_mfma_f32_16x16x32_bf16(ah[i], bl[j], acc[i][j], 0, 0, 0);
          acc[i][j] = __builtin_amdgcn_mfma_f32_16x16x32_bf16(al[i], bh[j], acc[i][j], 0, 0, 0);
        }
      }
  }

  // epilogue. C/D frag: col = lane&15, row = (lane>>4)*4 + reg  [m89-verified]
  const int lr = lane & 15;
  const int rj = (lane >> 4) * 4;
#pragma unroll
  for (int i = 0; i < 4; i++){
#pragma unroll
    for (int j = 0; j < 4; j++){
      int rowb = m0 + wm * 64 + i * 16 + rj;
      int col  = n0 + wn * 64 + j * 16 + lr;
      float bv = BIAS ? bias[col] : 0.f;
      f32x4 v = acc[i][j];
      if (OUTMODE == 0){
        float* o = (float*)out0 + (long long)z * sOz;
#pragma unroll
        for (int r = 0; r < 4; r++) o[(size_t)(rowb + r) * ldo + col] = v[r] + bv;
      } else if (OUTMODE == 1){
        u16* oh = (u16*)out0; u16* ol = (u16*)out1;
#pragma unroll
        for (int r = 0; r < 4; r++){
          float x = v[r] + bv;
          u16 h = f2bf(x);
          oh[(size_t)(rowb + r) * ldo + col] = h;
          ol[(size_t)(rowb + r) * ldo + col] = f2bf(x - bf2f(h));
        }
      } else { // transposed bf16: out[col*ldo + rowb .. rowb+3], contiguous 8B
        u16x4v t;
#pragma unroll
        for (int r = 0; r < 4; r++) t[r] = f2bf(v[r] + bv);
        *(u16x4v*)((u16*)out0 + (size_t)col * ldo + rowb) = t;
      }
    }
  }
}

// ---------------- row softmax: S fp32 [8192][2048] -> P bf16 ----------------
DEV float wred_max(float v){
#pragma unroll
  for (int o = 32; o; o >>= 1) v = fmaxf(v, __shfl_xor(v, o));
  return v;
}
DEV float wred_sum(float v){
#pragma unroll
  for (int o = 32; o; o >>= 1) v += __shfl_xor(v, o);
  return v;
}

__global__ __launch_bounds__(256) void softmax_rows(const float* __restrict__ S, u16* __restrict__ P){
  const int row = blockIdx.x;
  const int tid = threadIdx.x;
  const float* x = S + (size_t)row * 2048 + tid * 8;
  u16* p = P + (size_t)row * 2048 + tid * 8;
  float4 a = *(const float4*)x, b = *(const float4*)(x + 4);
  float v[8] = {a.x, a.y, a.z, a.w, b.x, b.y, b.z, b.w};
  __shared__ float red[4];

  float m = v[0];
#pragma unroll
  for (int j = 1; j < 8; j++) m = fmaxf(m, v[j]);
  m = wred_max(m);
  if ((tid & 63) == 0) red[tid >> 6] = m;
  __syncthreads();
  m = fmaxf(fmaxf(red[0], red[1]), fmaxf(red[2], red[3]));

  float s = 0.f;
#pragma unroll
  for (int j = 0; j < 8; j++){ v[j] = __expf(v[j] - m); s += v[j]; }
  s = wred_sum(s);
  __syncthreads();
  if ((tid & 63) == 0) red[tid >> 6] = s;
  __syncthreads();
  s = red[0] + red[1] + red[2] + red[3];

  float inv = 1.f / s;
  u16x8v o;
#pragma unroll
  for (int j = 0; j < 8; j++) o[j] = f2bf(v[j] * inv);
  *(u16x8v*)p = o;
}

// ---------------- residual + layernorm ----------------
__global__ __launch_bounds__(256) void resid_ln(const float* __restrict__ O, const float* __restrict__ query,
                                                const float* __restrict__ gamma, const float* __restrict__ beta,
                                                float* __restrict__ out){
  const int row = blockIdx.x;
  const int tid = threadIdx.x;
  const size_t base = (size_t)row * 1024 + tid * 4;
  float4 o4 = *(const float4*)(O + base);
  float4 q4 = *(const float4*)(query + base);
  float x[4] = {o4.x + q4.x, o4.y + q4.y, o4.z + q4.z, o4.w + q4.w};
  float s = 0.f, ss = 0.f;
#pragma unroll
  for (int j = 0; j < 4; j++){ s += x[j]; ss += x[j] * x[j]; }

  __shared__ float red[4];
  s = wred_sum(s);
  if ((tid & 63) == 0) red[tid >> 6] = s;
  __syncthreads();
  s = red[0] + red[1] + red[2] + red[3];
  ss = wred_sum(ss);
  __syncthreads();
  if ((tid & 63) == 0) red[tid >> 6] = ss;
  __syncthreads();
  ss = red[0] + red[1] + red[2] + red[3];

  float mu = s * (1.f / 1024.f);
  float var = ss * (1.f / 1024.f) - mu * mu;
  float rs = rsqrtf(var + 1e-5f);
  float4 g4 = *(const float4*)(gamma + tid * 4);
  float4 b4 = *(const float4*)(beta + tid * 4);
  float4 r;
  r.x = (x[0] - mu) * rs * g4.x + b4.x;
  r.y = (x[1] - mu) * rs * g4.y + b4.y;
  r.z = (x[2] - mu) * rs * g4.z + b4.z;
  r.w = (x[3] - mu) * rs * g4.w + b4.w;
  *(float4*)(out + base) = r;
}

// ---------------- launch ----------------
extern "C" void kernel_launch(void* const* d_in, const int* in_sizes, int n_in,
                              void* d_out, int out_size, void* d_ws, size_t ws_size,
                              hipStream_t stream){
  const float* query  = (const float*)d_in[0];
  const float* key_in = (const float*)d_in[1];
  const float* value  = (const float*)d_in[2];
  const float* Wq = (const float*)d_in[3];
  const float* bq = (const float*)d_in[4];
  const float* Wk = (const float*)d_in[5];
  const float* bk = (const float*)d_in[6];
  const float* Wv = (const float*)d_in[7];
  const float* bv = (const float*)d_in[8];
  const float* gamma = (const float*)d_in[9];
  const float* beta  = (const float*)d_in[10];

  const int B = 4, S = 2048, D = 1024;
  const int M = B * S;                 // 8192 tokens
  const size_t MB = 1ull << 20;
  char* ws = (char*)d_ws;

  u16* q_hi = (u16*)(ws + 0);
  u16* q_lo = (u16*)(ws + 16 * MB);
  u16* k_hi = (u16*)(ws + 32 * MB);
  u16* k_lo = (u16*)(ws + 48 * MB);
  u16* vT   = (u16*)(ws + 64 * MB);    // [1024][8192]
  u16* wt_qh = (u16*)(ws + 80 * MB);
  u16* wt_ql = (u16*)(ws + 82 * MB);
  u16* wt_kh = (u16*)(ws + 84 * MB);
  u16* wt_kl = (u16*)(ws + 86 * MB);
  u16* wt_vh = (u16*)(ws + 88 * MB);
  u16* wt_vl = (u16*)(ws + 90 * MB);
  float* Obuf = (float*)(ws + 92 * MB);
  u16* qx_hi = (u16*)(ws + 124 * MB);
  u16* qx_lo = (u16*)(ws + 140 * MB);
  u16* kx_hi = (u16*)(ws + 156 * MB);
  u16* kx_lo = (u16*)(ws + 172 * MB);
  u16* vx_hi = (u16*)(ws + 188 * MB);
  u16* vx_lo = (u16*)(ws + 204 * MB);
  float* Sbuf = (float*)(ws + 124 * MB);  // aliases qx/kx splits (consumed by then)
  u16*   Pbuf = (u16*)(ws + 188 * MB);    // aliases vx splits (consumed by then)

  dim3 blk(256);
  const int nElem = M * D;             // 8388608

  split_f32<<<nElem / 1024, blk, 0, stream>>>(query,  qx_hi, qx_lo, nElem);
  split_f32<<<nElem / 1024, blk, 0, stream>>>(key_in, kx_hi, kx_lo, nElem);
  split_f32<<<nElem / 1024, blk, 0, stream>>>(value,  vx_hi, vx_lo, nElem);

  dim3 tg(32, 32);
  transpose_split_w<<<tg, blk, 0, stream>>>(Wq, wt_qh, wt_ql, D);
  transpose_split_w<<<tg, blk, 0, stream>>>(Wk, wt_kh, wt_kl, D);
  transpose_split_w<<<tg, blk, 0, stream>>>(Wv, wt_vh, wt_vl, D);

  // Q, K projections: split GEMM, split epilogue. M=8192,N=1024,K=1024
  dim3 gp(D / 128, M / 128, 1);
  gemm_bt<true, 1, true><<<gp, blk, 0, stream>>>(qx_hi, qx_lo, D, 0, wt_qh, wt_ql, D, 0,
                                                 bq, q_hi, q_lo, D, 0, M, D, D);
  gemm_bt<true, 1, true><<<gp, blk, 0, stream>>>(kx_hi, kx_lo, D, 0, wt_kh, wt_kl, D, 0,
                                                 bk, k_hi, k_lo, D, 0, M, D, D);
  // V projection: plain bf16, transposed epilogue -> vT[f][token], ldo = 8192
  gemm_bt<false, 2, true><<<gp, blk, 0, stream>>>(vx_hi, nullptr, D, 0, wt_vh, nullptr, D, 0,
                                                  bv, vT, nullptr, M, 0, M, D, D);

  // QK^T per batch: M=N=2048, K=1024, split 3-MFMA, fp32 logits
  dim3 gs(S / 128, S / 128, B);
  gemm_bt<true, 0, false><<<gs, blk, 0, stream>>>(q_hi, q_lo, D, (long long)S * D,
                                                  k_hi, k_lo, D, (long long)S * D,
                                                  nullptr, Sbuf, nullptr, S, (long long)S * S,
                                                  S, S, D);

  softmax_rows<<<M, blk, 0, stream>>>(Sbuf, Pbuf);

  // PV per batch: M=2048, N=1024, K=2048. Bt = vT (ldb=8192, batch offset 2048 cols)
  dim3 gpv(D / 128, S / 128, B);
  gemm_bt<false, 0, false><<<gpv, blk, 0, stream>>>(Pbuf, nullptr, S, (long long)S * S,
                                                    vT, nullptr, M, (long long)S,
                                                    nullptr, Obuf, nullptr, D, (long long)S * D,
                                                    S, D, S);

  resid_ln<<<M, blk, 0, stream>>>(Obuf, query, gamma, beta, (float*)d_out);
}

// Round 2
// 289.759 us; speedup vs baseline: 1.3837x; 1.3837x over previous
//
#include <hip/hip_runtime.h>
#include <hip/hip_bf16.h>
#include <cstdint>

// SelfAttention fused pipeline, MI355X gfx950. Round 2: all-fp16 single-MFMA.
// B=4, S=2048, D=1024. fp32 in/out; internal fp16 MFMA for all GEMMs.
// Error budget: fp16 rounding (rel ~2.8e-4 std) -> logit err std ~0.013,
// worst-case prob shift ~0.02 -> output absmax ~0.05 vs threshold 0.104.
//
// ws layout (MB offsets):
//   @0   qf16  [8192][1024] fp16 (16MB)
//   @16  kf16  [8192][1024] fp16 (16MB)
//   @32  vT    [1024][8192] fp16 (16MB)   (features x tokens; batch = col chunk)
//   @48  wt_q, @50 wt_k, @52 wt_v  [f][d] fp16 (2MB each)
//   @54  Obuf  [8192][1024] fp32 (32MB)
//   @86  xq, @102 xk, @118 xv  [8192][1024] fp16 inputs (16MB each; dead after proj)
//   @134 Sbuf  [4][2048][2048] fp32 (64MB)
//   @86  Pbuf  [4][2048][2048] fp16 (32MB) -- aliases xq/xk (dead by softmax)
// total 198MB

typedef unsigned short u16;
typedef unsigned int   u32;
typedef _Float16 f16;
typedef f16   f16x8  __attribute__((ext_vector_type(8)));
typedef f16   f16x4  __attribute__((ext_vector_type(4)));
typedef float f32x4  __attribute__((ext_vector_type(4)));

#define DEV __device__ __forceinline__

// async global->LDS, 16B per lane. LDS dest must be linear (uniform base + lane*16).
DEV void gld_lds16(const void* g, void* l){
  __builtin_amdgcn_global_load_lds(
      (const __attribute__((address_space(1))) u32*)(uintptr_t)g,
      (__attribute__((address_space(3))) u32*)(u32)(uintptr_t)l, 16, 0, 0);
}

// ---------------- fp32 -> fp16 convert (8 elems/thread) ----------------
__global__ __launch_bounds__(256) void cvt_f32_f16(const float* __restrict__ x,
                                                   f16* __restrict__ y, int n){
  int i = (blockIdx.x * 256 + threadIdx.x) * 8;
  if (i >= n) return;
  float4 a = *(const float4*)(x + i);
  float4 b = *(const float4*)(x + i + 4);
  f16x8 v;
  v[0]=(f16)a.x; v[1]=(f16)a.y; v[2]=(f16)a.z; v[3]=(f16)a.w;
  v[4]=(f16)b.x; v[5]=(f16)b.y; v[6]=(f16)b.z; v[7]=(f16)b.w;
  *(f16x8*)(y + i) = v;
}

// ------------- W [d][f] fp32 -> Wt [f][d] fp16 (transpose + convert) -------------
__global__ __launch_bounds__(256) void transpose_cvt_w(const float* __restrict__ W,
                                                       f16* __restrict__ T, int D){
  __shared__ float t[32][33];
  int tx = threadIdx.x & 31, ty = threadIdx.x >> 5; // 32 x 8
  int bx = blockIdx.x * 32, by = blockIdx.y * 32;
#pragma unroll
  for (int j = 0; j < 4; j++) t[ty + j*8][tx] = W[(size_t)(by + ty + j*8) * D + bx + tx];
  __syncthreads();
#pragma unroll
  for (int j = 0; j < 4; j++){
    float v = t[tx][ty + j*8];                          // = W[by+tx][bx+ty+j*8]
    T[(size_t)(bx + ty + j*8) * D + by + tx] = (f16)v;  // T[f][d]
  }
}

// ---------------- MFMA GEMM: C[M][N] = A[M][K] * Bt[N][K]^T (+bias) ----------------
// OUTMODE: 0 = fp32 C[row*ldo+col]; 1 = fp16 C[row*ldo+col]; 2 = transposed fp16 C[col*ldo+row].
template<int OUTMODE, bool BIAS>
__global__ __launch_bounds__(256)
void gemm_bt(const f16* __restrict__ A, int lda, long long sAz,
             const f16* __restrict__ B, int ldb, long long sBz,
             const float* __restrict__ bias,
             void* __restrict__ out0, int ldo, long long sOz,
             int N, int K)
{
  constexpr int BM = 128, BN = 128, BK = 32;
  __shared__ f16 smem[2 * BM * BK];      // 16KB
  f16* sA = smem;
  f16* sB = smem + BM * BK;

  const int tid  = threadIdx.x;
  const int lane = tid & 63;
  const int w    = tid >> 6;          // 4 waves, 2x2
  const int wm   = w >> 1, wn = w & 1;
  const int z    = blockIdx.z;
  const int m0   = blockIdx.y * BM;
  const int n0   = blockIdx.x * BN;

  const f16* Ab = A + (long long)z * sAz + (size_t)m0 * lda;
  const f16* Bb = B + (long long)z * sBz + (size_t)n0 * ldb;

  auto stage = [&](const f16* g, int ld, f16* s){
#pragma unroll
    for (int i = 0; i < 2; i++){
      int o = (tid + i * 256) * 16;        // byte offset within 8KB tile
      int r = o >> 6;                      // row (64B = 32 halves per row)
      int cb = o & 63;                     // byte col
      gld_lds16((const char*)g + (size_t)r * ld * 2 + cb, (char*)s + o);
    }
  };

  f32x4 acc[4][4] = {};

  for (int k0 = 0; k0 < K; k0 += BK){
    __syncthreads();   // prev iter's LDS reads done before overwrite
    stage(Ab + k0, lda, sA);
    stage(Bb + k0, ldb, sB);
    __syncthreads();   // drains vmcnt(0): LDS tiles ready

    const int lr  = lane & 15;
    const int lkb = (lane >> 4) * 16;      // byte offset of this lane's k-chunk (8 halves)
    f16x8 a[4], b[4];
#pragma unroll
    for (int i = 0; i < 4; i++){
      a[i] = *(const f16x8*)((const char*)sA + ((wm * 64 + i * 16 + lr) * 64 + lkb));
      b[i] = *(const f16x8*)((const char*)sB + ((wn * 64 + i * 16 + lr) * 64 + lkb));
    }
#pragma unroll
    for (int i = 0; i < 4; i++)
#pragma unroll
      for (int j = 0; j < 4; j++)
        acc[i][j] = __builtin_amdgcn_mfma_f32_16x16x32_f16(a[i], b[j], acc[i][j], 0, 0, 0);
  }

  // epilogue. C/D frag: col = lane&15, row = (lane>>4)*4 + reg  [m89-verified]
  const int lr = lane & 15;
  const int rj = (lane >> 4) * 4;
#pragma unroll
  for (int i = 0; i < 4; i++){
#pragma unroll
    for (int j = 0; j < 4; j++){
      int rowb = m0 + wm * 64 + i * 16 + rj;
      int col  = n0 + wn * 64 + j * 16 + lr;
      float bv = BIAS ? bias[col] : 0.f;
      f32x4 v = acc[i][j];
      if (OUTMODE == 0){
        float* o = (float*)out0 + (long long)z * sOz;
#pragma unroll
        for (int r = 0; r < 4; r++) o[(size_t)(rowb + r) * ldo + col] = v[r] + bv;
      } else if (OUTMODE == 1){
        f16* o = (f16*)out0;
#pragma unroll
        for (int r = 0; r < 4; r++) o[(size_t)(rowb + r) * ldo + col] = (f16)(v[r] + bv);
      } else { // transposed fp16: out[col*ldo + rowb..rowb+3], contiguous 8B
        f16x4 t;
#pragma unroll
        for (int r = 0; r < 4; r++) t[r] = (f16)(v[r] + bv);
        *(f16x4*)((f16*)out0 + (size_t)col * ldo + rowb) = t;
      }
    }
  }
}

// ---------------- row softmax: S fp32 [8192][2048] -> P fp16 ----------------
DEV float wred_max(float v){
#pragma unroll
  for (int o = 32; o; o >>= 1) v = fmaxf(v, __shfl_xor(v, o));
  return v;
}
DEV float wred_sum(float v){
#pragma unroll
  for (int o = 32; o; o >>= 1) v += __shfl_xor(v, o);
  return v;
}

__global__ __launch_bounds__(256) void softmax_rows(const float* __restrict__ S, f16* __restrict__ P){
  const int row = blockIdx.x;
  const int tid = threadIdx.x;
  const float* x = S + (size_t)row * 2048 + tid * 8;
  f16* p = P + (size_t)row * 2048 + tid * 8;
  float4 a = *(const float4*)x, b = *(const float4*)(x + 4);
  float v[8] = {a.x, a.y, a.z, a.w, b.x, b.y, b.z, b.w};
  __shared__ float red[4];

  float m = v[0];
#pragma unroll
  for (int j = 1; j < 8; j++) m = fmaxf(m, v[j]);
  m = wred_max(m);
  if ((tid & 63) == 0) red[tid >> 6] = m;
  __syncthreads();
  m = fmaxf(fmaxf(red[0], red[1]), fmaxf(red[2], red[3]));

  float s = 0.f;
#pragma unroll
  for (int j = 0; j < 8; j++){ v[j] = __expf(v[j] - m); s += v[j]; }
  s = wred_sum(s);
  __syncthreads();
  if ((tid & 63) == 0) red[tid >> 6] = s;
  __syncthreads();
  s = red[0] + red[1] + red[2] + red[3];

  float inv = 1.f / s;
  f16x8 o;
#pragma unroll
  for (int j = 0; j < 8; j++) o[j] = (f16)(v[j] * inv);
  *(f16x8*)p = o;
}

// ---------------- residual + layernorm ----------------
__global__ __launch_bounds__(256) void resid_ln(const float* __restrict__ O, const float* __restrict__ query,
                                                const float* __restrict__ gamma, const float* __restrict__ beta,
                                                float* __restrict__ out){
  const int row = blockIdx.x;
  const int tid = threadIdx.x;
  const size_t base = (size_t)row * 1024 + tid * 4;
  float4 o4 = *(const float4*)(O + base);
  float4 q4 = *(const float4*)(query + base);
  float x[4] = {o4.x + q4.x, o4.y + q4.y, o4.z + q4.z, o4.w + q4.w};
  float s = 0.f, ss = 0.f;
#pragma unroll
  for (int j = 0; j < 4; j++){ s += x[j]; ss += x[j] * x[j]; }

  __shared__ float red[4];
  s = wred_sum(s);
  if ((tid & 63) == 0) red[tid >> 6] = s;
  __syncthreads();
  s = red[0] + red[1] + red[2] + red[3];
  ss = wred_sum(ss);
  __syncthreads();
  if ((tid & 63) == 0) red[tid >> 6] = ss;
  __syncthreads();
  ss = red[0] + red[1] + red[2] + red[3];

  float mu = s * (1.f / 1024.f);
  float var = ss * (1.f / 1024.f) - mu * mu;
  float rs = rsqrtf(var + 1e-5f);
  float4 g4 = *(const float4*)(gamma + tid * 4);
  float4 b4 = *(const float4*)(beta + tid * 4);
  float4 r;
  r.x = (x[0] - mu) * rs * g4.x + b4.x;
  r.y = (x[1] - mu) * rs * g4.y + b4.y;
  r.z = (x[2] - mu) * rs * g4.z + b4.z;
  r.w = (x[3] - mu) * rs * g4.w + b4.w;
  *(float4*)(out + base) = r;
}

// ---------------- launch ----------------
extern "C" void kernel_launch(void* const* d_in, const int* in_sizes, int n_in,
                              void* d_out, int out_size, void* d_ws, size_t ws_size,
                              hipStream_t stream){
  const float* query  = (const float*)d_in[0];
  const float* key_in = (const float*)d_in[1];
  const float* value  = (const float*)d_in[2];
  const float* Wq = (const float*)d_in[3];
  const float* bq = (const float*)d_in[4];
  const float* Wk = (const float*)d_in[5];
  const float* bk = (const float*)d_in[6];
  const float* Wv = (const float*)d_in[7];
  const float* bv = (const float*)d_in[8];
  const float* gamma = (const float*)d_in[9];
  const float* beta  = (const float*)d_in[10];

  const int B = 4, S = 2048, D = 1024;
  const int M = B * S;                 // 8192 tokens
  const size_t MB = 1ull << 20;
  char* ws = (char*)d_ws;

  f16* qf16 = (f16*)(ws + 0);
  f16* kf16 = (f16*)(ws + 16 * MB);
  f16* vT   = (f16*)(ws + 32 * MB);    // [1024][8192]
  f16* wt_q = (f16*)(ws + 48 * MB);
  f16* wt_k = (f16*)(ws + 50 * MB);
  f16* wt_v = (f16*)(ws + 52 * MB);
  float* Obuf = (float*)(ws + 54 * MB);
  f16* xq   = (f16*)(ws + 86 * MB);
  f16* xk   = (f16*)(ws + 102 * MB);
  f16* xv   = (f16*)(ws + 118 * MB);
  float* Sbuf = (float*)(ws + 134 * MB);  // 64MB
  f16*   Pbuf = (f16*)(ws + 86 * MB);     // aliases xq/xk (dead after projections)

  dim3 blk(256);
  const int nElem = M * D;             // 8388608

  cvt_f32_f16<<<nElem / 2048, blk, 0, stream>>>(query,  xq, nElem);
  cvt_f32_f16<<<nElem / 2048, blk, 0, stream>>>(key_in, xk, nElem);
  cvt_f32_f16<<<nElem / 2048, blk, 0, stream>>>(value,  xv, nElem);

  dim3 tg(32, 32);
  transpose_cvt_w<<<tg, blk, 0, stream>>>(Wq, wt_q, D);
  transpose_cvt_w<<<tg, blk, 0, stream>>>(Wk, wt_k, D);
  transpose_cvt_w<<<tg, blk, 0, stream>>>(Wv, wt_v, D);

  // Q, K projections: fp16 out. M=8192, N=1024, K=1024
  dim3 gp(D / 128, M / 128, 1);
  gemm_bt<1, true><<<gp, blk, 0, stream>>>(xq, D, 0, wt_q, D, 0, bq, qf16, D, 0, D, D);
  gemm_bt<1, true><<<gp, blk, 0, stream>>>(xk, D, 0, wt_k, D, 0, bk, kf16, D, 0, D, D);
  // V projection: transposed epilogue -> vT[f][token], ldo = 8192
  gemm_bt<2, true><<<gp, blk, 0, stream>>>(xv, D, 0, wt_v, D, 0, bv, vT, M, 0, D, D);

  // QK^T per batch: M=N=2048, K=1024, fp32 logits
  dim3 gs(S / 128, S / 128, B);
  gemm_bt<0, false><<<gs, blk, 0, stream>>>(qf16, D, (long long)S * D,
                                            kf16, D, (long long)S * D,
                                            nullptr, Sbuf, S, (long long)S * S, S, D);

  softmax_rows<<<M, blk, 0, stream>>>(Sbuf, Pbuf);

  // PV per batch: M=2048, N=1024, K=2048. Bt = vT (ldb=8192, batch offset 2048 cols)
  dim3 gpv(D / 128, S / 128, B);
  gemm_bt<0, false><<<gpv, blk, 0, stream>>>(Pbuf, S, (long long)S * S,
                                             vT, M, (long long)S,
                                             nullptr, Obuf, D, (long long)S * D, D, S);

  resid_ln<<<M, blk, 0, stream>>>(Obuf, query, gamma, beta, (float*)d_out);
}

// Round 3
// 208.968 us; speedup vs baseline: 1.9187x; 1.3866x over previous
//
#include <hip/hip_runtime.h>
#include <hip/hip_bf16.h>
#include <cstdint>

// SelfAttention fused pipeline, MI355X gfx950. Round 3: 256^2 8-phase GEMMs.
// B=4, S=2048, D=1024. fp32 in/out; fp16 MFMA internally (R2-validated numerics).
//
// GEMM structure (T2+T3+T4+T5): BM=BN=256, BK=64, 512 thr = 8 waves (2Mx4N,
// interleaved tiling), 128KiB LDS double-buffered. Per K-tile: 8 phases;
// stage 1 half-tile load/phase into buf^1 via global_load_lds (pre-swizzled
// global source, linear LDS dest); counted s_waitcnt vmcnt(5)@p0 / vmcnt(3)@p2
// + s_barrier (only 2 barriers per K-tile, never vmcnt(0) in steady state);
// setprio(1) around MFMA clusters.
//
// Race-freedom: stage order per tile = A0,B0,A1,B1 (2 issues each). Phases
// p0/p1 consume A0,B0 (oldest 4 issues -> vmcnt(5) with 1 new issue in
// flight); p2/p3 add B1, p4..p7 add A1 (all landed by vmcnt(3)@p2). Staging
// into buf^1 region R only after all reads of R finished >=1 barrier earlier.
//
// ws layout (MB offsets): 0 qf16(16) | 16 kf16(16) | 32 vT(16) | 48/50/52 wt
// | 54 O0(32) | 86 O1(32) | 118 xq(16) | 134 xk(16) | 150 xv(16)
// | 118 Sbuf fp32(64, aliases xq..xv after proj) ... wait: Sbuf @118..182
// | 182 Pbuf fp16(32). Total 214MB.

typedef unsigned short u16;
typedef unsigned int   u32;
typedef _Float16 f16;
typedef f16   f16x8  __attribute__((ext_vector_type(8)));
typedef f16   f16x4  __attribute__((ext_vector_type(4)));
typedef float f32x4  __attribute__((ext_vector_type(4)));

#define DEV __device__ __forceinline__

// async global->LDS, 16B per lane. LDS dest linear (uniform base + lane*16).
DEV void gld_lds16(const f16* g, char* l){
  __builtin_amdgcn_global_load_lds(
      (const __attribute__((address_space(1))) u32*)(uintptr_t)g,
      (__attribute__((address_space(3))) u32*)(u32)(uintptr_t)l, 16, 0, 0);
}

#define MFMA_(av, bv, ci, cj) \
  acc[ci][cj] = __builtin_amdgcn_mfma_f32_16x16x32_f16(av, bv, acc[ci][cj], 0, 0, 0)

// ---------------- 256x256 8-phase GEMM core ----------------
// C[256][256] tile = A[256][K] * B[256][K]^T, K = nt*64.
// A,B pre-offset to tile origin. acc[i][j]: m-frag i (rows i*32+wm*16+..),
// n-frag j (cols j*64+wn*16+..).
DEV void gemm_core(const f16* __restrict__ A, int lda,
                   const f16* __restrict__ B, int ldb,
                   int nt, char* smem, f32x4 (&acc)[8][4])
{
  const int tid  = threadIdx.x;
  const int lane = tid & 63;
  const int wv   = tid >> 6;
  const int wm   = wv >> 2, wn = wv & 3;
  const int lr   = lane & 15, lq = lane >> 4;

  // ---- staging source addresses (pre-swizzled global, m173/rule-21) ----
  // LDS region (16KB = 128 rows x 128B): physical slot sp=(o>>4)&7 holds
  // logical k-chunk sl = sp ^ (row&7).
  const int ob0 = tid * 16;          // sub-issue 0: rows 0..63
  const int ob1 = ob0 + 8192;        // sub-issue 1: rows 64..127
  const int r0  = ob0 >> 7, r1 = ob1 >> 7;
  const int sl0 = ((ob0 >> 4) & 7) ^ (r0 & 7);
  const int sl1 = ((ob1 >> 4) & 7) ^ (r1 & 7);
  const f16* src[8];
  src[0] = A + (size_t)r0 * lda + sl0 * 8;          // A half0
  src[1] = A + (size_t)r1 * lda + sl1 * 8;
  src[2] = B + (size_t)r0 * ldb + sl0 * 8;          // B half0
  src[3] = B + (size_t)r1 * ldb + sl1 * 8;
  src[4] = A + (size_t)(128 + r0) * lda + sl0 * 8;  // A half1
  src[5] = A + (size_t)(128 + r1) * lda + sl1 * 8;
  src[6] = B + (size_t)(128 + r0) * ldb + sl0 * 8;  // B half1
  src[7] = B + (size_t)(128 + r1) * ldb + sl1 * 8;

  // ---- ds_read address components (match the write-side swizzle) ----
  const int rA  = (wm * 16 + lr) << 7;          // row byte offset within half
  const int rB  = (wn * 16 + lr) << 7;
  const int sk0 = ((lq ^ (lane & 7)) << 4);         // ks=0 slot byte
  const int sk1 = (((4 | lq) ^ (lane & 7)) << 4);   // ks=1 slot byte

#pragma unroll
  for (int i = 0; i < 8; i++)
#pragma unroll
    for (int j = 0; j < 4; j++) acc[i][j] = (f32x4){0.f, 0.f, 0.f, 0.f};

  // ---- prologue: stage K-tile 0 into buf0 (issue order = A0,B0,A1,B1) ----
  gld_lds16(src[0], smem +     0 + ob0); src[0] += 64;
  gld_lds16(src[1], smem +     0 + ob1); src[1] += 64;
  gld_lds16(src[2], smem + 32768 + ob0); src[2] += 64;
  gld_lds16(src[3], smem + 32768 + ob1); src[3] += 64;
  gld_lds16(src[4], smem + 16384 + ob0); src[4] += 64;
  gld_lds16(src[5], smem + 16384 + ob1); src[5] += 64;
  gld_lds16(src[6], smem + 49152 + ob0); src[6] += 64;
  gld_lds16(src[7], smem + 49152 + ob1); src[7] += 64;

  for (int t = 0; t < nt; ++t){
    char* bufc  = smem + ((t & 1) << 16);
    char* stash = smem + (((t & 1) ^ 1) << 16);
    const bool more = (t + 1 < nt);

    f16x8 a0[4], a1[4], b0[2], b1[2], b2[2], b3[2];

    // -------- phase 0: A-half0 ks0 x B-half0 ks0 --------
    if (more){ gld_lds16(src[0], stash + 0 + ob0); src[0] += 64; }
    if (more) asm volatile("s_waitcnt vmcnt(5)\ns_barrier" ::: "memory");
    else      asm volatile("s_waitcnt vmcnt(4)\ns_barrier" ::: "memory");
#pragma unroll
    for (int i = 0; i < 4; i++) a0[i] = *(const f16x8*)(bufc + (i << 12) + rA + sk0);
    b0[0] = *(const f16x8*)(bufc + 32768 +    0 + rB + sk0);
    b0[1] = *(const f16x8*)(bufc + 32768 + 8192 + rB + sk0);
    __builtin_amdgcn_s_setprio(1);
#pragma unroll
    for (int i = 0; i < 4; i++){ MFMA_(a0[i], b0[0], i, 0); MFMA_(a0[i], b0[1], i, 1); }
    __builtin_amdgcn_s_setprio(0);

    // -------- phase 1: A-half0 ks1 x B-half0 ks1 --------
    if (more){ gld_lds16(src[1], stash + 0 + ob1); src[1] += 64; }
#pragma unroll
    for (int i = 0; i < 4; i++) a1[i] = *(const f16x8*)(bufc + (i << 12) + rA + sk1);
    b1[0] = *(const f16x8*)(bufc + 32768 +    0 + rB + sk1);
    b1[1] = *(const f16x8*)(bufc + 32768 + 8192 + rB + sk1);
    __builtin_amdgcn_s_setprio(1);
#pragma unroll
    for (int i = 0; i < 4; i++){ MFMA_(a1[i], b1[0], i, 0); MFMA_(a1[i], b1[1], i, 1); }
    __builtin_amdgcn_s_setprio(0);

    // -------- phase 2: A-half0 ks0 x B-half1 ks0 --------
    if (more){ gld_lds16(src[2], stash + 32768 + ob0); src[2] += 64; }
    if (more) asm volatile("s_waitcnt vmcnt(3)\ns_barrier" ::: "memory");
    else      asm volatile("s_waitcnt vmcnt(0)\ns_barrier" ::: "memory");
    b2[0] = *(const f16x8*)(bufc + 49152 +    0 + rB + sk0);
    b2[1] = *(const f16x8*)(bufc + 49152 + 8192 + rB + sk0);
    __builtin_amdgcn_s_setprio(1);
#pragma unroll
    for (int i = 0; i < 4; i++){ MFMA_(a0[i], b2[0], i, 2); MFMA_(a0[i], b2[1], i, 3); }
    __builtin_amdgcn_s_setprio(0);

    // -------- phase 3: A-half0 ks1 x B-half1 ks1 --------
    if (more){ gld_lds16(src[3], stash + 32768 + ob1); src[3] += 64; }
    b3[0] = *(const f16x8*)(bufc + 49152 +    0 + rB + sk1);
    b3[1] = *(const f16x8*)(bufc + 49152 + 8192 + rB + sk1);
    __builtin_amdgcn_s_setprio(1);
#pragma unroll
    for (int i = 0; i < 4; i++){ MFMA_(a1[i], b3[0], i, 2); MFMA_(a1[i], b3[1], i, 3); }
    __builtin_amdgcn_s_setprio(0);

    // -------- phase 4: A-half1 ks0 x B-half0 ks0 --------
    if (more){ gld_lds16(src[4], stash + 16384 + ob0); src[4] += 64; }
#pragma unroll
    for (int i = 0; i < 4; i++) a0[i] = *(const f16x8*)(bufc + 16384 + (i << 12) + rA + sk0);
    __builtin_amdgcn_s_setprio(1);
#pragma unroll
    for (int i = 0; i < 4; i++){ MFMA_(a0[i], b0[0], 4 + i, 0); MFMA_(a0[i], b0[1], 4 + i, 1); }
    __builtin_amdgcn_s_setprio(0);

    // -------- phase 5: A-half1 ks1 x B-half0 ks1 --------
    if (more){ gld_lds16(src[5], stash + 16384 + ob1); src[5] += 64; }
#pragma unroll
    for (int i = 0; i < 4; i++) a1[i] = *(const f16x8*)(bufc + 16384 + (i << 12) + rA + sk1);
    __builtin_amdgcn_s_setprio(1);
#pragma unroll
    for (int i = 0; i < 4; i++){ MFMA_(a1[i], b1[0], 4 + i, 0); MFMA_(a1[i], b1[1], 4 + i, 1); }
    __builtin_amdgcn_s_setprio(0);

    // -------- phase 6: A-half1 ks0 x B-half1 ks0 --------
    if (more){ gld_lds16(src[6], stash + 49152 + ob0); src[6] += 64; }
    __builtin_amdgcn_s_setprio(1);
#pragma unroll
    for (int i = 0; i < 4; i++){ MFMA_(a0[i], b2[0], 4 + i, 2); MFMA_(a0[i], b2[1], 4 + i, 3); }
    __builtin_amdgcn_s_setprio(0);

    // -------- phase 7: A-half1 ks1 x B-half1 ks1 --------
    if (more){ gld_lds16(src[7], stash + 49152 + ob1); src[7] += 64; }
    __builtin_amdgcn_s_setprio(1);
#pragma unroll
    for (int i = 0; i < 4; i++){ MFMA_(a1[i], b3[0], 4 + i, 2); MFMA_(a1[i], b3[1], 4 + i, 3); }
    __builtin_amdgcn_s_setprio(0);
  }
}

// ---------------- fused Q/K/V projections ----------------
__global__ __launch_bounds__(512, 2) void proj8p(
    const f16* __restrict__ xq, const f16* __restrict__ xk, const f16* __restrict__ xv,
    const f16* __restrict__ wq, const f16* __restrict__ wk, const f16* __restrict__ wv,
    const float* __restrict__ bq, const float* __restrict__ bk, const float* __restrict__ bv,
    f16* __restrict__ oq, f16* __restrict__ ok, f16* __restrict__ ovT)
{
  __shared__ char smem[131072];
  const int z  = blockIdx.z;
  const int m0 = blockIdx.y * 256, n0 = blockIdx.x * 256;
  const f16* A = (z == 0 ? xq : z == 1 ? xk : xv) + (size_t)m0 * 1024;
  const f16* B = (z == 0 ? wq : z == 1 ? wk : wv) + (size_t)n0 * 1024;
  const float* bias = (z == 0 ? bq : z == 1 ? bk : bv);

  f32x4 acc[8][4];
  gemm_core(A, 1024, B, 1024, 16, smem, acc);

  const int lane = threadIdx.x & 63;
  const int wv_  = threadIdx.x >> 6;
  const int wm = wv_ >> 2, wn = wv_ & 3;
  const int lr = lane & 15, rj = (lane >> 4) * 4;

  if (z < 2){
    f16* o = z ? ok : oq;
#pragma unroll
    for (int i = 0; i < 8; i++)
#pragma unroll
      for (int j = 0; j < 4; j++){
        int row = m0 + i * 32 + wm * 16 + rj;
        int col = n0 + j * 64 + wn * 16 + lr;
        float bvl = bias[col];
#pragma unroll
        for (int r = 0; r < 4; r++)
          o[(size_t)(row + r) * 1024 + col] = (f16)(acc[i][j][r] + bvl);
      }
  } else { // V: transposed fp16 -> ovT[feature][8192 tokens]
#pragma unroll
    for (int i = 0; i < 8; i++)
#pragma unroll
      for (int j = 0; j < 4; j++){
        int row = m0 + i * 32 + wm * 16 + rj;
        int col = n0 + j * 64 + wn * 16 + lr;
        float bvl = bias[col];
        f16x4 tv;
#pragma unroll
        for (int r = 0; r < 4; r++) tv[r] = (f16)(acc[i][j][r] + bvl);
        *(f16x4*)(ovT + (size_t)col * 8192 + row) = tv;
      }
  }
}

// ---------------- QK^T (per batch, fp32 logits) ----------------
__global__ __launch_bounds__(512, 2) void qk8p(
    const f16* __restrict__ q, const f16* __restrict__ k, float* __restrict__ Sout)
{
  __shared__ char smem[131072];
  const int z  = blockIdx.z;
  const int m0 = blockIdx.y * 256, n0 = blockIdx.x * 256;
  const f16* A = q + (size_t)z * 2048 * 1024 + (size_t)m0 * 1024;
  const f16* B = k + (size_t)z * 2048 * 1024 + (size_t)n0 * 1024;

  f32x4 acc[8][4];
  gemm_core(A, 1024, B, 1024, 16, smem, acc);

  const int lane = threadIdx.x & 63;
  const int wv_  = threadIdx.x >> 6;
  const int wm = wv_ >> 2, wn = wv_ & 3;
  const int lr = lane & 15, rj = (lane >> 4) * 4;
  float* o = Sout + (size_t)z * 2048 * 2048;
#pragma unroll
  for (int i = 0; i < 8; i++)
#pragma unroll
    for (int j = 0; j < 4; j++){
      int row = m0 + i * 32 + wm * 16 + rj;
      int col = n0 + j * 64 + wn * 16 + lr;
#pragma unroll
      for (int r = 0; r < 4; r++)
        o[(size_t)(row + r) * 2048 + col] = acc[i][j][r];
    }
}

// ---------------- PV (per batch, split-K x2 -> O0/O1 partials) ----------------
__global__ __launch_bounds__(512, 2) void pv8p(
    const f16* __restrict__ P, const f16* __restrict__ vT, float* __restrict__ O)
{
  __shared__ char smem[131072];
  const int z  = blockIdx.z;
  const int zb = z >> 1, h = z & 1;
  const int m0 = blockIdx.y * 256, n0 = blockIdx.x * 256;
  const f16* A = P  + (size_t)zb * 2048 * 2048 + (size_t)m0 * 2048 + h * 1024;
  const f16* B = vT + (size_t)n0 * 8192 + (size_t)zb * 2048 + h * 1024;

  f32x4 acc[8][4];
  gemm_core(A, 2048, B, 8192, 16, smem, acc);

  const int lane = threadIdx.x & 63;
  const int wv_  = threadIdx.x >> 6;
  const int wm = wv_ >> 2, wn = wv_ & 3;
  const int lr = lane & 15, rj = (lane >> 4) * 4;
  float* o = O + (size_t)h * 8388608 + (size_t)zb * 2048 * 1024;
#pragma unroll
  for (int i = 0; i < 8; i++)
#pragma unroll
    for (int j = 0; j < 4; j++){
      int row = m0 + i * 32 + wm * 16 + rj;
      int col = n0 + j * 64 + wn * 16 + lr;
#pragma unroll
      for (int r = 0; r < 4; r++)
        o[(size_t)(row + r) * 1024 + col] = acc[i][j][r];
    }
}

// ---------------- fp32 -> fp16 convert (8 elems/thread) ----------------
__global__ __launch_bounds__(256) void cvt_f32_f16(const float* __restrict__ x,
                                                   f16* __restrict__ y, int n){
  int i = (blockIdx.x * 256 + threadIdx.x) * 8;
  if (i >= n) return;
  float4 a = *(const float4*)(x + i);
  float4 b = *(const float4*)(x + i + 4);
  f16x8 v;
  v[0]=(f16)a.x; v[1]=(f16)a.y; v[2]=(f16)a.z; v[3]=(f16)a.w;
  v[4]=(f16)b.x; v[5]=(f16)b.y; v[6]=(f16)b.z; v[7]=(f16)b.w;
  *(f16x8*)(y + i) = v;
}

// ------------- W [d][f] fp32 -> Wt [f][d] fp16 (transpose + convert) -------------
__global__ __launch_bounds__(256) void transpose_cvt_w(const float* __restrict__ W,
                                                       f16* __restrict__ T, int D){
  __shared__ float t[32][33];
  int tx = threadIdx.x & 31, ty = threadIdx.x >> 5; // 32 x 8
  int bx = blockIdx.x * 32, by = blockIdx.y * 32;
#pragma unroll
  for (int j = 0; j < 4; j++) t[ty + j*8][tx] = W[(size_t)(by + ty + j*8) * D + bx + tx];
  __syncthreads();
#pragma unroll
  for (int j = 0; j < 4; j++){
    float v = t[tx][ty + j*8];
    T[(size_t)(bx + ty + j*8) * D + by + tx] = (f16)v;
  }
}

// ---------------- row softmax: S fp32 [8192][2048] -> P fp16 ----------------
DEV float wred_max(float v){
#pragma unroll
  for (int o = 32; o; o >>= 1) v = fmaxf(v, __shfl_xor(v, o));
  return v;
}
DEV float wred_sum(float v){
#pragma unroll
  for (int o = 32; o; o >>= 1) v += __shfl_xor(v, o);
  return v;
}

__global__ __launch_bounds__(256) void softmax_rows(const float* __restrict__ S, f16* __restrict__ P){
  const int row = blockIdx.x;
  const int tid = threadIdx.x;
  const float* x = S + (size_t)row * 2048 + tid * 8;
  f16* p = P + (size_t)row * 2048 + tid * 8;
  float4 a = *(const float4*)x, b = *(const float4*)(x + 4);
  float v[8] = {a.x, a.y, a.z, a.w, b.x, b.y, b.z, b.w};
  __shared__ float red[4];

  float m = v[0];
#pragma unroll
  for (int j = 1; j < 8; j++) m = fmaxf(m, v[j]);
  m = wred_max(m);
  if ((tid & 63) == 0) red[tid >> 6] = m;
  __syncthreads();
  m = fmaxf(fmaxf(red[0], red[1]), fmaxf(red[2], red[3]));

  float s = 0.f;
#pragma unroll
  for (int j = 0; j < 8; j++){ v[j] = __expf(v[j] - m); s += v[j]; }
  s = wred_sum(s);
  __syncthreads();
  if ((tid & 63) == 0) red[tid >> 6] = s;
  __syncthreads();
  s = red[0] + red[1] + red[2] + red[3];

  float inv = 1.f / s;
  f16x8 o;
#pragma unroll
  for (int j = 0; j < 8; j++) o[j] = (f16)(v[j] * inv);
  *(f16x8*)p = o;
}

// ---------------- residual + layernorm (sums two O partials) ----------------
__global__ __launch_bounds__(256) void resid_ln2(const float* __restrict__ O0,
                                                 const float* __restrict__ O1,
                                                 const float* __restrict__ query,
                                                 const float* __restrict__ gamma,
                                                 const float* __restrict__ beta,
                                                 float* __restrict__ out){
  const int row = blockIdx.x;
  const int tid = threadIdx.x;
  const size_t base = (size_t)row * 1024 + tid * 4;
  float4 o4 = *(const float4*)(O0 + base);
  float4 p4 = *(const float4*)(O1 + base);
  float4 q4 = *(const float4*)(query + base);
  float x[4] = {o4.x + p4.x + q4.x, o4.y + p4.y + q4.y,
                o4.z + p4.z + q4.z, o4.w + p4.w + q4.w};
  float s = 0.f, ss = 0.f;
#pragma unroll
  for (int j = 0; j < 4; j++){ s += x[j]; ss += x[j] * x[j]; }

  __shared__ float red[4];
  s = wred_sum(s);
  if ((tid & 63) == 0) red[tid >> 6] = s;
  __syncthreads();
  s = red[0] + red[1] + red[2] + red[3];
  ss = wred_sum(ss);
  __syncthreads();
  if ((tid & 63) == 0) red[tid >> 6] = ss;
  __syncthreads();
  ss = red[0] + red[1] + red[2] + red[3];

  float mu = s * (1.f / 1024.f);
  float var = ss * (1.f / 1024.f) - mu * mu;
  float rs = rsqrtf(var + 1e-5f);
  float4 g4 = *(const float4*)(gamma + tid * 4);
  float4 b4 = *(const float4*)(beta + tid * 4);
  float4 r;
  r.x = (x[0] - mu) * rs * g4.x + b4.x;
  r.y = (x[1] - mu) * rs * g4.y + b4.y;
  r.z = (x[2] - mu) * rs * g4.z + b4.z;
  r.w = (x[3] - mu) * rs * g4.w + b4.w;
  *(float4*)(out + base) = r;
}

// ---------------- launch ----------------
extern "C" void kernel_launch(void* const* d_in, const int* in_sizes, int n_in,
                              void* d_out, int out_size, void* d_ws, size_t ws_size,
                              hipStream_t stream){
  const float* query  = (const float*)d_in[0];
  const float* key_in = (const float*)d_in[1];
  const float* value  = (const float*)d_in[2];
  const float* Wq = (const float*)d_in[3];
  const float* bq = (const float*)d_in[4];
  const float* Wk = (const float*)d_in[5];
  const float* bk = (const float*)d_in[6];
  const float* Wv = (const float*)d_in[7];
  const float* bv = (const float*)d_in[8];
  const float* gamma = (const float*)d_in[9];
  const float* beta  = (const float*)d_in[10];

  const int B = 4, S = 2048, D = 1024;
  const int M = B * S;                 // 8192 tokens
  const size_t MB = 1ull << 20;
  char* ws = (char*)d_ws;

  f16* qf16 = (f16*)(ws + 0);
  f16* kf16 = (f16*)(ws + 16 * MB);
  f16* vT   = (f16*)(ws + 32 * MB);    // [1024][8192]
  f16* wt_q = (f16*)(ws + 48 * MB);
  f16* wt_k = (f16*)(ws + 50 * MB);
  f16* wt_v = (f16*)(ws + 52 * MB);
  float* Obuf = (float*)(ws + 54 * MB);   // O0 @54, O1 @86 (32MB each)
  f16* xq   = (f16*)(ws + 118 * MB);
  f16* xk   = (f16*)(ws + 134 * MB);
  f16* xv   = (f16*)(ws + 150 * MB);
  float* Sbuf = (float*)(ws + 118 * MB);  // 64MB, aliases xq..xv (dead after proj)
  f16*   Pbuf = (f16*)(ws + 182 * MB);    // 32MB

  dim3 blk(256);
  const int nElem = M * D;             // 8388608

  cvt_f32_f16<<<nElem / 2048, blk, 0, stream>>>(query,  xq, nElem);
  cvt_f32_f16<<<nElem / 2048, blk, 0, stream>>>(key_in, xk, nElem);
  cvt_f32_f16<<<nElem / 2048, blk, 0, stream>>>(value,  xv, nElem);

  dim3 tg(32, 32);
  transpose_cvt_w<<<tg, blk, 0, stream>>>(Wq, wt_q, D);
  transpose_cvt_w<<<tg, blk, 0, stream>>>(Wk, wt_k, D);
  transpose_cvt_w<<<tg, blk, 0, stream>>>(Wv, wt_v, D);

  // fused projections: grid (N/256, M/256, 3), 512 threads
  proj8p<<<dim3(4, 32, 3), dim3(512), 0, stream>>>(xq, xk, xv, wt_q, wt_k, wt_v,
                                                   bq, bk, bv, qf16, kf16, vT);

  // QK^T per batch: 256 WGs
  qk8p<<<dim3(8, 8, 4), dim3(512), 0, stream>>>(qf16, kf16, Sbuf);

  softmax_rows<<<M, blk, 0, stream>>>(Sbuf, Pbuf);

  // PV per batch, split-K x2: 256 WGs
  pv8p<<<dim3(4, 8, 8), dim3(512), 0, stream>>>(Pbuf, vT, Obuf);

  resid_ln2<<<M, blk, 0, stream>>>(Obuf, Obuf + 8388608, query, gamma, beta, (float*)d_out);
}

// Round 4
// 195.610 us; speedup vs baseline: 2.0497x; 1.0683x over previous
//
#include <hip/hip_runtime.h>
#include <hip/hip_bf16.h>
#include <cstdint>

// SelfAttention fused pipeline, MI355X gfx950. Round 4:
//  R3 (256^2 8-phase counted-vmcnt GEMM core) + T1 XCD swizzle in all GEMMs
//  + peeled epilogue K-tile (unconditional hot loop) + merged prepasses.
// B=4, S=2048, D=1024. fp32 in/out; fp16 MFMA internally.
//
// ws layout (MB offsets): 0 qf16(16) | 16 kf16(16) | 32 vT(16) | 48/50/52 wt
// | 54 O0(32) | 86 O1(32) | 118 xq(16) | 134 xk(16) | 150 xv(16)
// | 118 Sbuf fp32(64, aliases xq..xv after proj) | 182 Pbuf fp16(32).

typedef unsigned short u16;
typedef unsigned int   u32;
typedef _Float16 f16;
typedef f16   f16x8  __attribute__((ext_vector_type(8)));
typedef f16   f16x4  __attribute__((ext_vector_type(4)));
typedef float f32x4  __attribute__((ext_vector_type(4)));

#define DEV __device__ __forceinline__

// async global->LDS, 16B per lane. LDS dest linear (uniform base + lane*16).
DEV void gld_lds16(const f16* g, char* l){
  __builtin_amdgcn_global_load_lds(
      (const __attribute__((address_space(1))) u32*)(uintptr_t)g,
      (__attribute__((address_space(3))) u32*)(u32)(uintptr_t)l, 16, 0, 0);
}

// T1: bijective XCD-contiguous remap of the linearized block id.
// orig%8 = XCD of original dispatch slot -> give each XCD a contiguous chunk.
DEV int swz_lid(){
  int lid = (blockIdx.z * gridDim.y + blockIdx.y) * gridDim.x + blockIdx.x;
  int cpx = (gridDim.x * gridDim.y * gridDim.z) >> 3;   // grids are %8==0
  return (lid & 7) * cpx + (lid >> 3);
}

#define MFMA_(av, bv, ci, cj) \
  acc[ci][cj] = __builtin_amdgcn_mfma_f32_16x16x32_f16(av, bv, acc[ci][cj], 0, 0, 0)

// ---------------- one K-tile body (8 phases) ----------------
// MORE: stage next tile into stash + counted vmcnt; else drain.
template<bool MORE>
DEV void ktile_body(const f16* (&src)[8], char* bufc, char* stash,
                    int ob0, int ob1, int rA, int rB, int sk0, int sk1,
                    f32x4 (&acc)[8][4])
{
  f16x8 a0[4], a1[4], b0[2], b1[2], b2[2], b3[2];

  // -------- phase 0 --------
  if (MORE){ gld_lds16(src[0], stash + 0 + ob0); src[0] += 64; }
  if (MORE) asm volatile("s_waitcnt vmcnt(5)\ns_barrier" ::: "memory");
  else      asm volatile("s_waitcnt vmcnt(4)\ns_barrier" ::: "memory");
#pragma unroll
  for (int i = 0; i < 4; i++) a0[i] = *(const f16x8*)(bufc + (i << 12) + rA + sk0);
  b0[0] = *(const f16x8*)(bufc + 32768 +    0 + rB + sk0);
  b0[1] = *(const f16x8*)(bufc + 32768 + 8192 + rB + sk0);
  __builtin_amdgcn_s_setprio(1);
#pragma unroll
  for (int i = 0; i < 4; i++){ MFMA_(a0[i], b0[0], i, 0); MFMA_(a0[i], b0[1], i, 1); }
  __builtin_amdgcn_s_setprio(0);

  // -------- phase 1 --------
  if (MORE){ gld_lds16(src[1], stash + 0 + ob1); src[1] += 64; }
#pragma unroll
  for (int i = 0; i < 4; i++) a1[i] = *(const f16x8*)(bufc + (i << 12) + rA + sk1);
  b1[0] = *(const f16x8*)(bufc + 32768 +    0 + rB + sk1);
  b1[1] = *(const f16x8*)(bufc + 32768 + 8192 + rB + sk1);
  __builtin_amdgcn_s_setprio(1);
#pragma unroll
  for (int i = 0; i < 4; i++){ MFMA_(a1[i], b1[0], i, 0); MFMA_(a1[i], b1[1], i, 1); }
  __builtin_amdgcn_s_setprio(0);

  // -------- phase 2 --------
  if (MORE){ gld_lds16(src[2], stash + 32768 + ob0); src[2] += 64; }
  if (MORE) asm volatile("s_waitcnt vmcnt(3)\ns_barrier" ::: "memory");
  else      asm volatile("s_waitcnt vmcnt(0)\ns_barrier" ::: "memory");
  b2[0] = *(const f16x8*)(bufc + 49152 +    0 + rB + sk0);
  b2[1] = *(const f16x8*)(bufc + 49152 + 8192 + rB + sk0);
  __builtin_amdgcn_s_setprio(1);
#pragma unroll
  for (int i = 0; i < 4; i++){ MFMA_(a0[i], b2[0], i, 2); MFMA_(a0[i], b2[1], i, 3); }
  __builtin_amdgcn_s_setprio(0);

  // -------- phase 3 --------
  if (MORE){ gld_lds16(src[3], stash + 32768 + ob1); src[3] += 64; }
  b3[0] = *(const f16x8*)(bufc + 49152 +    0 + rB + sk1);
  b3[1] = *(const f16x8*)(bufc + 49152 + 8192 + rB + sk1);
  __builtin_amdgcn_s_setprio(1);
#pragma unroll
  for (int i = 0; i < 4; i++){ MFMA_(a1[i], b3[0], i, 2); MFMA_(a1[i], b3[1], i, 3); }
  __builtin_amdgcn_s_setprio(0);

  // -------- phase 4 --------
  if (MORE){ gld_lds16(src[4], stash + 16384 + ob0); src[4] += 64; }
#pragma unroll
  for (int i = 0; i < 4; i++) a0[i] = *(const f16x8*)(bufc + 16384 + (i << 12) + rA + sk0);
  __builtin_amdgcn_s_setprio(1);
#pragma unroll
  for (int i = 0; i < 4; i++){ MFMA_(a0[i], b0[0], 4 + i, 0); MFMA_(a0[i], b0[1], 4 + i, 1); }
  __builtin_amdgcn_s_setprio(0);

  // -------- phase 5 --------
  if (MORE){ gld_lds16(src[5], stash + 16384 + ob1); src[5] += 64; }
#pragma unroll
  for (int i = 0; i < 4; i++) a1[i] = *(const f16x8*)(bufc + 16384 + (i << 12) + rA + sk1);
  __builtin_amdgcn_s_setprio(1);
#pragma unroll
  for (int i = 0; i < 4; i++){ MFMA_(a1[i], b1[0], 4 + i, 0); MFMA_(a1[i], b1[1], 4 + i, 1); }
  __builtin_amdgcn_s_setprio(0);

  // -------- phase 6 --------
  if (MORE){ gld_lds16(src[6], stash + 49152 + ob0); src[6] += 64; }
  __builtin_amdgcn_s_setprio(1);
#pragma unroll
  for (int i = 0; i < 4; i++){ MFMA_(a0[i], b2[0], 4 + i, 2); MFMA_(a0[i], b2[1], 4 + i, 3); }
  __builtin_amdgcn_s_setprio(0);

  // -------- phase 7 --------
  if (MORE){ gld_lds16(src[7], stash + 49152 + ob1); src[7] += 64; }
  __builtin_amdgcn_s_setprio(1);
#pragma unroll
  for (int i = 0; i < 4; i++){ MFMA_(a1[i], b3[0], 4 + i, 2); MFMA_(a1[i], b3[1], 4 + i, 3); }
  __builtin_amdgcn_s_setprio(0);
}

// ---------------- 256x256 8-phase GEMM core ----------------
DEV void gemm_core(const f16* __restrict__ A, int lda,
                   const f16* __restrict__ B, int ldb,
                   int nt, char* smem, f32x4 (&acc)[8][4])
{
  const int tid  = threadIdx.x;
  const int lane = tid & 63;
  const int wv   = tid >> 6;
  const int wm   = wv >> 2, wn = wv & 3;
  const int lr   = lane & 15, lq = lane >> 4;

  // staging source addresses (pre-swizzled global, m173/rule-21):
  // LDS 16KB region = 128 rows x 128B; physical slot sp=(o>>4)&7 holds
  // logical k-chunk sl = sp ^ (row&7).
  const int ob0 = tid * 16;
  const int ob1 = ob0 + 8192;
  const int r0  = ob0 >> 7, r1 = ob1 >> 7;
  const int sl0 = ((ob0 >> 4) & 7) ^ (r0 & 7);
  const int sl1 = ((ob1 >> 4) & 7) ^ (r1 & 7);
  const f16* src[8];
  src[0] = A + (size_t)r0 * lda + sl0 * 8;
  src[1] = A + (size_t)r1 * lda + sl1 * 8;
  src[2] = B + (size_t)r0 * ldb + sl0 * 8;
  src[3] = B + (size_t)r1 * ldb + sl1 * 8;
  src[4] = A + (size_t)(128 + r0) * lda + sl0 * 8;
  src[5] = A + (size_t)(128 + r1) * lda + sl1 * 8;
  src[6] = B + (size_t)(128 + r0) * ldb + sl0 * 8;
  src[7] = B + (size_t)(128 + r1) * ldb + sl1 * 8;

  const int rA  = (wm * 16 + lr) << 7;
  const int rB  = (wn * 16 + lr) << 7;
  const int sk0 = ((lq ^ (lane & 7)) << 4);
  const int sk1 = (((4 | lq) ^ (lane & 7)) << 4);

#pragma unroll
  for (int i = 0; i < 8; i++)
#pragma unroll
    for (int j = 0; j < 4; j++) acc[i][j] = (f32x4){0.f, 0.f, 0.f, 0.f};

  // prologue: stage K-tile 0 into buf0 (issue order = A0,B0,A1,B1)
  gld_lds16(src[0], smem +     0 + ob0); src[0] += 64;
  gld_lds16(src[1], smem +     0 + ob1); src[1] += 64;
  gld_lds16(src[2], smem + 32768 + ob0); src[2] += 64;
  gld_lds16(src[3], smem + 32768 + ob1); src[3] += 64;
  gld_lds16(src[4], smem + 16384 + ob0); src[4] += 64;
  gld_lds16(src[5], smem + 16384 + ob1); src[5] += 64;
  gld_lds16(src[6], smem + 49152 + ob0); src[6] += 64;
  gld_lds16(src[7], smem + 49152 + ob1); src[7] += 64;

  for (int t = 0; t < nt - 1; ++t){
    char* bufc  = smem + ((t & 1) << 16);
    char* stash = smem + (((t & 1) ^ 1) << 16);
    ktile_body<true>(src, bufc, stash, ob0, ob1, rA, rB, sk0, sk1, acc);
  }
  {
    char* bufc  = smem + (((nt - 1) & 1) << 16);
    char* stash = smem + ((((nt - 1) & 1) ^ 1) << 16);
    ktile_body<false>(src, bufc, stash, ob0, ob1, rA, rB, sk0, sk1, acc);
  }
}

// ---------------- fused Q/K/V projections ----------------
__global__ __launch_bounds__(512, 2) void proj8p(
    const f16* __restrict__ xq, const f16* __restrict__ xk, const f16* __restrict__ xv,
    const f16* __restrict__ wq, const f16* __restrict__ wk, const f16* __restrict__ wv,
    const float* __restrict__ bq, const float* __restrict__ bk, const float* __restrict__ bv,
    f16* __restrict__ oq, f16* __restrict__ ok, f16* __restrict__ ovT)
{
  __shared__ char smem[131072];
  const int s  = swz_lid();               // grid (4, 32, 3)
  const int bx = s & 3, by = (s >> 2) & 31, z = s >> 7;
  const int m0 = by * 256, n0 = bx * 256;
  const f16* A = (z == 0 ? xq : z == 1 ? xk : xv) + (size_t)m0 * 1024;
  const f16* B = (z == 0 ? wq : z == 1 ? wk : wv) + (size_t)n0 * 1024;
  const float* bias = (z == 0 ? bq : z == 1 ? bk : bv);

  f32x4 acc[8][4];
  gemm_core(A, 1024, B, 1024, 16, smem, acc);

  const int lane = threadIdx.x & 63;
  const int wv_  = threadIdx.x >> 6;
  const int wm = wv_ >> 2, wn = wv_ & 3;
  const int lr = lane & 15, rj = (lane >> 4) * 4;

  if (z < 2){
    f16* o = z ? ok : oq;
#pragma unroll
    for (int i = 0; i < 8; i++)
#pragma unroll
      for (int j = 0; j < 4; j++){
        int row = m0 + i * 32 + wm * 16 + rj;
        int col = n0 + j * 64 + wn * 16 + lr;
        float bvl = bias[col];
#pragma unroll
        for (int r = 0; r < 4; r++)
          o[(size_t)(row + r) * 1024 + col] = (f16)(acc[i][j][r] + bvl);
      }
  } else { // V: transposed fp16 -> ovT[feature][8192 tokens]
#pragma unroll
    for (int i = 0; i < 8; i++)
#pragma unroll
      for (int j = 0; j < 4; j++){
        int row = m0 + i * 32 + wm * 16 + rj;
        int col = n0 + j * 64 + wn * 16 + lr;
        float bvl = bias[col];
        f16x4 tv;
#pragma unroll
        for (int r = 0; r < 4; r++) tv[r] = (f16)(acc[i][j][r] + bvl);
        *(f16x4*)(ovT + (size_t)col * 8192 + row) = tv;
      }
  }
}

// ---------------- QK^T (per batch, fp32 logits) ----------------
__global__ __launch_bounds__(512, 2) void qk8p(
    const f16* __restrict__ q, const f16* __restrict__ k, float* __restrict__ Sout)
{
  __shared__ char smem[131072];
  const int s  = swz_lid();               // grid (8, 8, 4)
  const int bx = s & 7, by = (s >> 3) & 7, z = s >> 6;
  const int m0 = by * 256, n0 = bx * 256;
  const f16* A = q + (size_t)z * 2048 * 1024 + (size_t)m0 * 1024;
  const f16* B = k + (size_t)z * 2048 * 1024 + (size_t)n0 * 1024;

  f32x4 acc[8][4];
  gemm_core(A, 1024, B, 1024, 16, smem, acc);

  const int lane = threadIdx.x & 63;
  const int wv_  = threadIdx.x >> 6;
  const int wm = wv_ >> 2, wn = wv_ & 3;
  const int lr = lane & 15, rj = (lane >> 4) * 4;
  float* o = Sout + (size_t)z * 2048 * 2048;
#pragma unroll
  for (int i = 0; i < 8; i++)
#pragma unroll
    for (int j = 0; j < 4; j++){
      int row = m0 + i * 32 + wm * 16 + rj;
      int col = n0 + j * 64 + wn * 16 + lr;
#pragma unroll
      for (int r = 0; r < 4; r++)
        o[(size_t)(row + r) * 2048 + col] = acc[i][j][r];
    }
}

// ---------------- PV (per batch, split-K x2 -> O0/O1 partials) ----------------
__global__ __launch_bounds__(512, 2) void pv8p(
    const f16* __restrict__ P, const f16* __restrict__ vT, float* __restrict__ O)
{
  __shared__ char smem[131072];
  const int s  = swz_lid();               // grid (4, 8, 8)
  const int bx = s & 3, by = (s >> 2) & 7, z = s >> 5;
  const int zb = z >> 1, h = z & 1;
  const int m0 = by * 256, n0 = bx * 256;
  const f16* A = P  + (size_t)zb * 2048 * 2048 + (size_t)m0 * 2048 + h * 1024;
  const f16* B = vT + (size_t)n0 * 8192 + (size_t)zb * 2048 + h * 1024;

  f32x4 acc[8][4];
  gemm_core(A, 2048, B, 8192, 16, smem, acc);

  const int lane = threadIdx.x & 63;
  const int wv_  = threadIdx.x >> 6;
  const int wm = wv_ >> 2, wn = wv_ & 3;
  const int lr = lane & 15, rj = (lane >> 4) * 4;
  float* o = O + (size_t)h * 8388608 + (size_t)zb * 2048 * 1024;
#pragma unroll
  for (int i = 0; i < 8; i++)
#pragma unroll
    for (int j = 0; j < 4; j++){
      int row = m0 + i * 32 + wm * 16 + rj;
      int col = n0 + j * 64 + wn * 16 + lr;
#pragma unroll
      for (int r = 0; r < 4; r++)
        o[(size_t)(row + r) * 1024 + col] = acc[i][j][r];
    }
}

// ---------------- fp32 -> fp16 convert, 3 tensors in one launch ----------------
__global__ __launch_bounds__(256) void cvt3_f32_f16(
    const float* __restrict__ x0, const float* __restrict__ x1, const float* __restrict__ x2,
    f16* __restrict__ y0, f16* __restrict__ y1, f16* __restrict__ y2){
  const int z = blockIdx.y;
  const float* x = z == 0 ? x0 : z == 1 ? x1 : x2;
  f16* y = z == 0 ? y0 : z == 1 ? y1 : y2;
  int i = (blockIdx.x * 256 + threadIdx.x) * 8;
  float4 a = *(const float4*)(x + i);
  float4 b = *(const float4*)(x + i + 4);
  f16x8 v;
  v[0]=(f16)a.x; v[1]=(f16)a.y; v[2]=(f16)a.z; v[3]=(f16)a.w;
  v[4]=(f16)b.x; v[5]=(f16)b.y; v[6]=(f16)b.z; v[7]=(f16)b.w;
  *(f16x8*)(y + i) = v;
}

// ------------- W [d][f] fp32 -> Wt [f][d] fp16, 3 weights in one launch -------------
__global__ __launch_bounds__(256) void transpose3_cvt_w(
    const float* __restrict__ W0, const float* __restrict__ W1, const float* __restrict__ W2,
    f16* __restrict__ T0, f16* __restrict__ T1, f16* __restrict__ T2, int D){
  const int z = blockIdx.z;
  const float* W = z == 0 ? W0 : z == 1 ? W1 : W2;
  f16* T = z == 0 ? T0 : z == 1 ? T1 : T2;
  __shared__ float t[32][33];
  int tx = threadIdx.x & 31, ty = threadIdx.x >> 5; // 32 x 8
  int bx = blockIdx.x * 32, by = blockIdx.y * 32;
#pragma unroll
  for (int j = 0; j < 4; j++) t[ty + j*8][tx] = W[(size_t)(by + ty + j*8) * D + bx + tx];
  __syncthreads();
#pragma unroll
  for (int j = 0; j < 4; j++){
    float v = t[tx][ty + j*8];
    T[(size_t)(bx + ty + j*8) * D + by + tx] = (f16)v;
  }
}

// ---------------- row softmax: S fp32 [8192][2048] -> P fp16 ----------------
DEV float wred_max(float v){
#pragma unroll
  for (int o = 32; o; o >>= 1) v = fmaxf(v, __shfl_xor(v, o));
  return v;
}
DEV float wred_sum(float v){
#pragma unroll
  for (int o = 32; o; o >>= 1) v += __shfl_xor(v, o);
  return v;
}

__global__ __launch_bounds__(256) void softmax_rows(const float* __restrict__ S, f16* __restrict__ P){
  const int row = blockIdx.x;
  const int tid = threadIdx.x;
  const float* x = S + (size_t)row * 2048 + tid * 8;
  f16* p = P + (size_t)row * 2048 + tid * 8;
  float4 a = *(const float4*)x, b = *(const float4*)(x + 4);
  float v[8] = {a.x, a.y, a.z, a.w, b.x, b.y, b.z, b.w};
  __shared__ float red[4];

  float m = v[0];
#pragma unroll
  for (int j = 1; j < 8; j++) m = fmaxf(m, v[j]);
  m = wred_max(m);
  if ((tid & 63) == 0) red[tid >> 6] = m;
  __syncthreads();
  m = fmaxf(fmaxf(red[0], red[1]), fmaxf(red[2], red[3]));

  float s = 0.f;
#pragma unroll
  for (int j = 0; j < 8; j++){ v[j] = __expf(v[j] - m); s += v[j]; }
  s = wred_sum(s);
  __syncthreads();
  if ((tid & 63) == 0) red[tid >> 6] = s;
  __syncthreads();
  s = red[0] + red[1] + red[2] + red[3];

  float inv = 1.f / s;
  f16x8 o;
#pragma unroll
  for (int j = 0; j < 8; j++) o[j] = (f16)(v[j] * inv);
  *(f16x8*)p = o;
}

// ---------------- residual + layernorm (sums two O partials) ----------------
__global__ __launch_bounds__(256) void resid_ln2(const float* __restrict__ O0,
                                                 const float* __restrict__ O1,
                                                 const float* __restrict__ query,
                                                 const float* __restrict__ gamma,
                                                 const float* __restrict__ beta,
                                                 float* __restrict__ out){
  const int row = blockIdx.x;
  const int tid = threadIdx.x;
  const size_t base = (size_t)row * 1024 + tid * 4;
  float4 o4 = *(const float4*)(O0 + base);
  float4 p4 = *(const float4*)(O1 + base);
  float4 q4 = *(const float4*)(query + base);
  float x[4] = {o4.x + p4.x + q4.x, o4.y + p4.y + q4.y,
                o4.z + p4.z + q4.z, o4.w + p4.w + q4.w};
  float s = 0.f, ss = 0.f;
#pragma unroll
  for (int j = 0; j < 4; j++){ s += x[j]; ss += x[j] * x[j]; }

  __shared__ float red[4];
  s = wred_sum(s);
  if ((tid & 63) == 0) red[tid >> 6] = s;
  __syncthreads();
  s = red[0] + red[1] + red[2] + red[3];
  ss = wred_sum(ss);
  __syncthreads();
  if ((tid & 63) == 0) red[tid >> 6] = ss;
  __syncthreads();
  ss = red[0] + red[1] + red[2] + red[3];

  float mu = s * (1.f / 1024.f);
  float var = ss * (1.f / 1024.f) - mu * mu;
  float rs = rsqrtf(var + 1e-5f);
  float4 g4 = *(const float4*)(gamma + tid * 4);
  float4 b4 = *(const float4*)(beta + tid * 4);
  float4 r;
  r.x = (x[0] - mu) * rs * g4.x + b4.x;
  r.y = (x[1] - mu) * rs * g4.y + b4.y;
  r.z = (x[2] - mu) * rs * g4.z + b4.z;
  r.w = (x[3] - mu) * rs * g4.w + b4.w;
  *(float4*)(out + base) = r;
}

// ---------------- launch ----------------
extern "C" void kernel_launch(void* const* d_in, const int* in_sizes, int n_in,
                              void* d_out, int out_size, void* d_ws, size_t ws_size,
                              hipStream_t stream){
  const float* query  = (const float*)d_in[0];
  const float* key_in = (const float*)d_in[1];
  const float* value  = (const float*)d_in[2];
  const float* Wq = (const float*)d_in[3];
  const float* bq = (const float*)d_in[4];
  const float* Wk = (const float*)d_in[5];
  const float* bk = (const float*)d_in[6];
  const float* Wv = (const float*)d_in[7];
  const float* bv = (const float*)d_in[8];
  const float* gamma = (const float*)d_in[9];
  const float* beta  = (const float*)d_in[10];

  const int B = 4, S = 2048, D = 1024;
  const int M = B * S;                 // 8192 tokens
  const size_t MB = 1ull << 20;
  char* ws = (char*)d_ws;

  f16* qf16 = (f16*)(ws + 0);
  f16* kf16 = (f16*)(ws + 16 * MB);
  f16* vT   = (f16*)(ws + 32 * MB);    // [1024][8192]
  f16* wt_q = (f16*)(ws + 48 * MB);
  f16* wt_k = (f16*)(ws + 50 * MB);
  f16* wt_v = (f16*)(ws + 52 * MB);
  float* Obuf = (float*)(ws + 54 * MB);   // O0 @54, O1 @86 (32MB each)
  f16* xq   = (f16*)(ws + 118 * MB);
  f16* xk   = (f16*)(ws + 134 * MB);
  f16* xv   = (f16*)(ws + 150 * MB);
  float* Sbuf = (float*)(ws + 118 * MB);  // 64MB, aliases xq..xv (dead after proj)
  f16*   Pbuf = (f16*)(ws + 182 * MB);    // 32MB

  dim3 blk(256);
  const int nElem = M * D;             // 8388608

  cvt3_f32_f16<<<dim3(nElem / 2048, 3), blk, 0, stream>>>(query, key_in, value, xq, xk, xv);
  transpose3_cvt_w<<<dim3(32, 32, 3), blk, 0, stream>>>(Wq, Wk, Wv, wt_q, wt_k, wt_v, D);

  // fused projections: grid (N/256, M/256, 3), 512 threads
  proj8p<<<dim3(4, 32, 3), dim3(512), 0, stream>>>(xq, xk, xv, wt_q, wt_k, wt_v,
                                                   bq, bk, bv, qf16, kf16, vT);

  // QK^T per batch: 256 WGs
  qk8p<<<dim3(8, 8, 4), dim3(512), 0, stream>>>(qf16, kf16, Sbuf);

  softmax_rows<<<M, blk, 0, stream>>>(Sbuf, Pbuf);

  // PV per batch, split-K x2: 256 WGs
  pv8p<<<dim3(4, 8, 8), dim3(512), 0, stream>>>(Pbuf, vT, Obuf);

  resid_ln2<<<M, blk, 0, stream>>>(Obuf, Obuf + 8388608, query, gamma, beta, (float*)d_out);
}